// Round 1
// baseline (650.613 us; speedup 1.0000x reference)
//
#include <hip/hip_runtime.h>
#include <hip/hip_bf16.h>
#include <stdint.h>

typedef short short8 __attribute__((ext_vector_type(8)));
typedef float f32x4 __attribute__((ext_vector_type(4)));

#define EPS_Z 1e-6f

__device__ __forceinline__ unsigned short f2bf(float f) {
  uint32_t b = __float_as_uint(f);
  b += 0x7FFFu + ((b >> 16) & 1u);   // RNE
  return (unsigned short)(b >> 16);
}
__device__ __forceinline__ float bf2f(unsigned short u) {
  return __uint_as_float(((uint32_t)u) << 16);
}

__device__ __forceinline__ void gl16(const unsigned short* g, unsigned short* l) {
  __builtin_amdgcn_global_load_lds(
      (const __attribute__((address_space(1))) unsigned int*)g,
      (__attribute__((address_space(3))) unsigned int*)l, 16, 0, 0);
}

// ---------------- P: fp32 -> bf16 convert (n multiple of 8) ----------------
__global__ __launch_bounds__(256) void k_cvt(const float* __restrict__ in,
                                             unsigned short* __restrict__ out, int n) {
  int i = (blockIdx.x * 256 + threadIdx.x) * 8;
  if (i >= n) return;
  float4 a = *(const float4*)(in + i);
  float4 b = *(const float4*)(in + i + 4);
  union { unsigned short u[8]; short8 v; } r;
  r.u[0] = f2bf(a.x); r.u[1] = f2bf(a.y); r.u[2] = f2bf(a.z); r.u[3] = f2bf(a.w);
  r.u[4] = f2bf(b.x); r.u[5] = f2bf(b.y); r.u[6] = f2bf(b.z); r.u[7] = f2bf(b.w);
  *(short8*)(out + i) = r.v;
}

// ---------------- A/E: projection GEMM + fused reductions ----------------
// MODE 0: k = elu(x@Wk^T+bk)+1, *mask; writes kd[bm][t][head], ksum_part[bm][trow][col]
// MODE 1: q = elu(x@Wq^T+bq)+1; writes Z[bm][head][t] = 1/(q . ksum + eps)
// grid (512 rowTiles, 6 colTiles), 256 threads (4 waves, 2x2, each 64x64 of 128x128 tile)
template <int MODE>
__global__ __launch_bounds__(256) void k_proj(
    const unsigned short* __restrict__ xbf,   // [65536][768] bf16
    const unsigned short* __restrict__ Wbf,   // [768][768] bf16
    const float* __restrict__ bias,           // [768]
    const float* __restrict__ mask,           // [128][512]      (MODE 0)
    const float* __restrict__ ksum_part,      // [128][4][768]   (MODE 1 input)
    float* __restrict__ out0,                 // MODE0: kd ; MODE1: Z
    float* __restrict__ out1)                 // MODE0: ksum_part
{
  __shared__ unsigned short Ab[128][64];   // 16KB
  __shared__ unsigned short Bb[128][64];   // 16KB
  __shared__ float rowf[128];
  __shared__ float ksl[128];
  __shared__ float kcol[2][128];

  const int tid = threadIdx.x;
  const int lane = tid & 63;
  const int wid = tid >> 6;
  const int wr = wid >> 1, wc = wid & 1;
  const int rowTile = blockIdx.x;   // 0..511
  const int colTile = blockIdx.y;   // 0..5
  const int bm = rowTile >> 2;
  const int trow = rowTile & 3;
  const size_t rowBase = (size_t)rowTile * 128;
  const int colBase = colTile * 128;
  const int lrow = lane & 15;
  const int lgrp = lane >> 4;

  if (MODE == 0) {
    if (tid < 128) rowf[tid] = mask[bm * 512 + trow * 128 + tid];
  } else {
    if (tid < 128) {
      const float* kp = ksum_part + (size_t)bm * 4 * 768 + colBase + tid;
      ksl[tid] = kp[0] + kp[768] + kp[1536] + kp[2304];
    }
  }

  f32x4 acc[4][4] = {};

  for (int kt = 0; kt < 12; ++kt) {
    const int k0 = kt * 64;
    __syncthreads();
#pragma unroll
    for (int c = 0; c < 4; ++c) {
      const int chunk = c * 256 + tid;
      const int r = chunk >> 3, kc = (chunk & 7) * 8;
      gl16(xbf + (rowBase + r) * 768 + k0 + kc,
           &Ab[0][0] + (c * 2048 + wid * 512));
      gl16(Wbf + (size_t)(colBase + r) * 768 + k0 + kc,
           &Bb[0][0] + (c * 2048 + wid * 512));
    }
    __syncthreads();
#pragma unroll
    for (int kk = 0; kk < 64; kk += 32) {
      short8 av[4], bv4[4];
#pragma unroll
      for (int rf = 0; rf < 4; ++rf)
        av[rf] = *(const short8*)&Ab[wr * 64 + rf * 16 + lrow][kk + lgrp * 8];
#pragma unroll
      for (int cf = 0; cf < 4; ++cf)
        bv4[cf] = *(const short8*)&Bb[wc * 64 + cf * 16 + lrow][kk + lgrp * 8];
#pragma unroll
      for (int rf = 0; rf < 4; ++rf)
#pragma unroll
        for (int cf = 0; cf < 4; ++cf)
          acc[rf][cf] = __builtin_amdgcn_mfma_f32_16x16x32_bf16(
              av[rf], bv4[cf], acc[rf][cf], 0, 0, 0);
    }
  }

  // epilogue: bias + elu+1 (+mask), in place
  float bvv[4];
#pragma unroll
  for (int cf = 0; cf < 4; ++cf)
    bvv[cf] = bias[colBase + wc * 64 + cf * 16 + lrow];
#pragma unroll
  for (int rf = 0; rf < 4; ++rf)
#pragma unroll
    for (int cf = 0; cf < 4; ++cf)
#pragma unroll
      for (int j = 0; j < 4; ++j) {
        float v = acc[rf][cf][j] + bvv[cf];
        v = (v > 0.0f) ? (v + 1.0f) : __expf(v);
        if (MODE == 0) v *= rowf[wr * 64 + rf * 16 + lgrp * 4 + j];
        acc[rf][cf][j] = v;
      }

  const int head = colTile * 2 + wc;   // wave covers exactly one head (64 cols)

  // per-row reduction over the head's 64 cols: kd (MODE0) or q.ksum -> Z (MODE1)
#pragma unroll
  for (int rf = 0; rf < 4; ++rf)
#pragma unroll
    for (int j = 0; j < 4; ++j) {
      float s;
      if (MODE == 0) {
        s = acc[rf][0][j] + acc[rf][1][j] + acc[rf][2][j] + acc[rf][3][j];
      } else {
        s = acc[rf][0][j] * ksl[wc * 64 + 0 + lrow]
          + acc[rf][1][j] * ksl[wc * 64 + 16 + lrow]
          + acc[rf][2][j] * ksl[wc * 64 + 32 + lrow]
          + acc[rf][3][j] * ksl[wc * 64 + 48 + lrow];
      }
      s += __shfl_xor(s, 1, 64);
      s += __shfl_xor(s, 2, 64);
      s += __shfl_xor(s, 4, 64);
      s += __shfl_xor(s, 8, 64);
      if ((lane & 15) == 0) {
        const int t = trow * 128 + wr * 64 + rf * 16 + lgrp * 4 + j;
        if (MODE == 0)
          out0[((size_t)bm * 512 + t) * 12 + head] = s;
        else
          out0[((size_t)bm * 12 + head) * 512 + t] = 1.0f / (s + EPS_Z);
      }
    }

  if (MODE == 0) {
    // column sums (ksum partial over this 128-row tile)
#pragma unroll
    for (int cf = 0; cf < 4; ++cf) {
      float s = 0.f;
#pragma unroll
      for (int rf = 0; rf < 4; ++rf)
#pragma unroll
        for (int j = 0; j < 4; ++j) s += acc[rf][cf][j];
      s += __shfl_xor(s, 16, 64);
      s += __shfl_xor(s, 32, 64);
      if (lane < 16) kcol[wr][wc * 64 + cf * 16 + lane] = s;
    }
    __syncthreads();
    if (tid < 128)
      out1[((size_t)bm * 4 + trow) * 768 + colBase + tid] =
          kcol[0][tid] + kcol[1][tid];
  }
}

// ---------------- C: xk_part[bm][th][n][c] = sum_t kd[t][n] * x[t][c] ----------------
__global__ __launch_bounds__(192) void k_xk(const unsigned short* __restrict__ xbf,
                                            const float* __restrict__ kd,
                                            float* __restrict__ xk_part) {
  __shared__ float kdl[256][12];
  const int bm = blockIdx.x, th = blockIdx.y, tid = threadIdx.x;
  for (int i = tid; i < 256 * 12; i += 192)
    kdl[i / 12][i % 12] = kd[((size_t)bm * 512 + th * 256 + i / 12) * 12 + (i % 12)];
  __syncthreads();
  float a[12][4];
#pragma unroll
  for (int n = 0; n < 12; ++n)
#pragma unroll
    for (int j = 0; j < 4; ++j) a[n][j] = 0.f;
  const int c = tid * 4;
  const unsigned short* xp = xbf + ((size_t)bm * 512 + th * 256) * 768 + c;
  for (int t = 0; t < 256; ++t) {
    ushort4 xv = *(const ushort4*)(xp + (size_t)t * 768);
    const float x0 = bf2f(xv.x), x1 = bf2f(xv.y), x2 = bf2f(xv.z), x3 = bf2f(xv.w);
#pragma unroll
    for (int n = 0; n < 12; ++n) {
      const float kv = kdl[t][n];
      a[n][0] += kv * x0; a[n][1] += kv * x1; a[n][2] += kv * x2; a[n][3] += kv * x3;
    }
  }
  float* op = xk_part + (size_t)(bm * 2 + th) * 12 * 768 + c;
#pragma unroll
  for (int n = 0; n < 12; ++n)
    *(float4*)(op + (size_t)n * 768) = make_float4(a[n][0], a[n][1], a[n][2], a[n][3]);
}

// ---------------- D: S[n][e] then G[n][p], per bm ----------------
__global__ __launch_bounds__(256) void k_sg(const float* __restrict__ ksum_part,
                                            const float* __restrict__ xk_part,
                                            const float* __restrict__ Wv,
                                            const float* __restrict__ bv,
                                            const float* __restrict__ Wp,
                                            float* __restrict__ G) {
  __shared__ float ksum_l[768];
  __shared__ float kdsum_l[12];
  __shared__ __align__(16) float xk_l[12 * 768];
  __shared__ __align__(16) float S_l[12 * 64];
  const int bm = blockIdx.x, tid = threadIdx.x;
  for (int i = tid; i < 768; i += 256) {
    const float* kp = ksum_part + (size_t)bm * 4 * 768 + i;
    ksum_l[i] = kp[0] + kp[768] + kp[1536] + kp[2304];
  }
  for (int i = tid; i < 9216; i += 256) {
    const float* xp = xk_part + (size_t)bm * 2 * 9216 + i;
    xk_l[i] = xp[0] + xp[9216];
  }
  __syncthreads();
  if (tid < 12) {
    float s = 0.f;
    for (int d = 0; d < 64; ++d) s += ksum_l[tid * 64 + d];
    kdsum_l[tid] = s;
  }
  __syncthreads();
  for (int o = tid; o < 768; o += 256) {
    const int n = o >> 6;
    const float4* wv = (const float4*)(Wv + (size_t)o * 768);
    const float4* xp = (const float4*)(xk_l + n * 768);
    float s = 0.f;
    for (int c4 = 0; c4 < 192; ++c4) {
      float4 w = wv[c4], xx = xp[c4];
      s += w.x * xx.x + w.y * xx.y + w.z * xx.z + w.w * xx.w;
    }
    S_l[o] = s + bv[o] * kdsum_l[n];
  }
  __syncthreads();
  for (int p = tid; p < 768; p += 256) {
    const float4* wp = (const float4*)(Wp + (size_t)p * 768);
    for (int n = 0; n < 12; ++n) {
      const float4* sp = (const float4*)(S_l + n * 64);
      float g = 0.f;
#pragma unroll
      for (int e4 = 0; e4 < 16; ++e4) {
        float4 w = wp[n * 16 + e4], s = sp[e4];
        g += w.x * s.x + w.y * s.y + w.z * s.z + w.w * s.w;
      }
      G[((size_t)bm * 12 + n) * 768 + p] = g;
    }
  }
}

// ---------------- F: out[t][p] = bp[p] + sum_n Z[n][t]*G[n][p] ----------------
__global__ __launch_bounds__(256) void k_out(const float* __restrict__ Z,
                                             const float* __restrict__ G,
                                             const float* __restrict__ bp,
                                             float* __restrict__ outp) {
  __shared__ __align__(16) float G_l[9216];
  __shared__ float Z_l[768];
  __shared__ __align__(16) float bp_l[768];
  const int bm = blockIdx.x;
  const int tbase = blockIdx.y * 64;
  const int tid = threadIdx.x;
  for (int i = tid; i < 9216; i += 256) G_l[i] = G[(size_t)bm * 9216 + i];
  for (int i = tid; i < 768; i += 256) {
    bp_l[i] = bp[i];
    Z_l[i] = Z[((size_t)bm * 12 + (i >> 6)) * 512 + tbase + (i & 63)];
  }
  __syncthreads();
  for (int it = 0; it < 48; ++it) {
    const int idx = it * 1024 + tid * 4;
    const int t = idx / 768;
    const int p = idx - t * 768;
    float4 o = *(const float4*)&bp_l[p];
#pragma unroll
    for (int n = 0; n < 12; ++n) {
      const float z = Z_l[n * 64 + t];
      const float4 g = *(const float4*)&G_l[n * 768 + p];
      o.x += z * g.x; o.y += z * g.y; o.z += z * g.z; o.w += z * g.w;
    }
    *(float4*)&outp[((size_t)bm * 512 + tbase + t) * 768 + p] = o;
  }
}

extern "C" void kernel_launch(void* const* d_in, const int* in_sizes, int n_in,
                              void* d_out, int out_size, void* d_ws, size_t ws_size,
                              hipStream_t stream) {
  const float* x    = (const float*)d_in[0];
  const float* mask = (const float*)d_in[1];
  const float* Wq   = (const float*)d_in[2];
  const float* bq   = (const float*)d_in[3];
  const float* Wk   = (const float*)d_in[4];
  const float* bk   = (const float*)d_in[5];
  const float* Wv   = (const float*)d_in[6];
  const float* bv   = (const float*)d_in[7];
  const float* Wp   = (const float*)d_in[8];
  const float* bp   = (const float*)d_in[9];
  float* outp = (float*)d_out;

  char* ws = (char*)d_ws;
  unsigned short* xbf  = (unsigned short*)(ws);                  // 100,663,296 B
  unsigned short* Wkbf = (unsigned short*)(ws + 100663296);      //   1,179,648
  unsigned short* Wqbf = (unsigned short*)(ws + 101842944);      //   1,179,648
  float* kd        = (float*)(ws + 103022592);                   //   3,145,728
  float* ksum_part = (float*)(ws + 106168320);                   //   1,572,864
  float* xk_part   = (float*)(ws + 107741184);                   //   9,437,184
  float* Zb        = (float*)(ws + 117178368);                   //   3,145,728
  float* G         = (float*)(ws + 120324096);                   //   4,718,592
  // total ws: 125,042,688 B

  hipLaunchKernelGGL(k_cvt, dim3(24576), dim3(256), 0, stream, x, xbf, 50331648);
  hipLaunchKernelGGL(k_cvt, dim3(288), dim3(256), 0, stream, Wk, Wkbf, 589824);
  hipLaunchKernelGGL(k_cvt, dim3(288), dim3(256), 0, stream, Wq, Wqbf, 589824);
  hipLaunchKernelGGL((k_proj<0>), dim3(512, 6), dim3(256), 0, stream,
                     xbf, Wkbf, bk, mask, (const float*)nullptr, kd, ksum_part);
  hipLaunchKernelGGL(k_xk, dim3(128, 2), dim3(192), 0, stream, xbf, kd, xk_part);
  hipLaunchKernelGGL(k_sg, dim3(128), dim3(256), 0, stream,
                     ksum_part, xk_part, Wv, bv, Wp, G);
  hipLaunchKernelGGL((k_proj<1>), dim3(512, 6), dim3(256), 0, stream,
                     xbf, Wqbf, bq, (const float*)nullptr, ksum_part, Zb,
                     (float*)nullptr);
  hipLaunchKernelGGL(k_out, dim3(128, 8), dim3(256), 0, stream, Zb, G, bp, outp);
}

// Round 2
// 572.752 us; speedup vs baseline: 1.1359x; 1.1359x over previous
//
#include <hip/hip_runtime.h>
#include <hip/hip_bf16.h>
#include <stdint.h>

typedef short short8 __attribute__((ext_vector_type(8)));
typedef float f32x4 __attribute__((ext_vector_type(4)));

#define EPS_Z 1e-6f

__device__ __forceinline__ unsigned short f2bf(float f) {
  uint32_t b = __float_as_uint(f);
  b += 0x7FFFu + ((b >> 16) & 1u);   // RNE
  return (unsigned short)(b >> 16);
}
__device__ __forceinline__ float bf2f(unsigned short u) {
  return __uint_as_float(((uint32_t)u) << 16);
}

__device__ __forceinline__ void gl16(const unsigned short* g, unsigned short* l) {
  __builtin_amdgcn_global_load_lds(
      (const __attribute__((address_space(1))) unsigned int*)g,
      (__attribute__((address_space(3))) unsigned int*)l, 16, 0, 0);
}

// ---------------- P: fp32 -> bf16 convert (n multiple of 8) ----------------
__global__ __launch_bounds__(256) void k_cvt(const float* __restrict__ in,
                                             unsigned short* __restrict__ out, int n) {
  int i = (blockIdx.x * 256 + threadIdx.x) * 8;
  if (i >= n) return;
  float4 a = *(const float4*)(in + i);
  float4 b = *(const float4*)(in + i + 4);
  union { unsigned short u[8]; short8 v; } r;
  r.u[0] = f2bf(a.x); r.u[1] = f2bf(a.y); r.u[2] = f2bf(a.z); r.u[3] = f2bf(a.w);
  r.u[4] = f2bf(b.x); r.u[5] = f2bf(b.y); r.u[6] = f2bf(b.z); r.u[7] = f2bf(b.w);
  *(short8*)(out + i) = r.v;
}

// ---------------- A/E: projection GEMM + fused reductions ----------------
// MODE 0: k = elu(x@Wk^T+bk)+1, *mask; writes kd[bm][t][head], ksum_part[bm][trow][col]
// MODE 1: q = elu(x@Wq^T+bq)+1; writes Z[bm][head][t] = 1/(q . ksum + eps)
// grid (6 colTiles, 512 rowTiles) -- colTile fastest so the concurrent window
// covers all 6 colTiles of each rowTile (x tile HBM-fetched once, L3 re-read).
// 256 threads (4 waves, 2x2, each 64x64 of the 128x128 tile).
// LDS tiles are XOR-swizzled at 16B-chunk granularity (chunk ^= row&7):
// linear gl16 dest + inverse-swizzled GLOBAL source + swizzled ds_read (rule 21).
template <int MODE>
__global__ __launch_bounds__(256) void k_proj(
    const unsigned short* __restrict__ xbf,   // [65536][768] bf16
    const unsigned short* __restrict__ Wbf,   // [768][768] bf16
    const float* __restrict__ bias,           // [768]
    const float* __restrict__ mask,           // [128][512]      (MODE 0)
    const float* __restrict__ ksum_part,      // [128][4][768]   (MODE 1 input)
    float* __restrict__ out0,                 // MODE0: kd ; MODE1: Z
    float* __restrict__ out1)                 // MODE0: ksum_part
{
  __shared__ unsigned short Ab[128][64];   // 16KB
  __shared__ unsigned short Bb[128][64];   // 16KB
  __shared__ float rowf[128];
  __shared__ float ksl[128];
  __shared__ float kcol[2][128];

  const int tid = threadIdx.x;
  const int lane = tid & 63;
  const int wid = tid >> 6;
  const int wr = wid >> 1, wc = wid & 1;
  const int colTile = blockIdx.x;   // 0..5
  const int rowTile = blockIdx.y;   // 0..511
  const int bm = rowTile >> 2;
  const int trow = rowTile & 3;
  const size_t rowBase = (size_t)rowTile * 128;
  const int colBase = colTile * 128;
  const int lrow = lane & 15;
  const int lgrp = lane >> 4;

  if (MODE == 0) {
    if (tid < 128) rowf[tid] = mask[bm * 512 + trow * 128 + tid];
  } else {
    if (tid < 128) {
      const float* kp = ksum_part + (size_t)bm * 4 * 768 + colBase + tid;
      ksl[tid] = kp[0] + kp[768] + kp[1536] + kp[2304];
    }
  }

  f32x4 acc[4][4] = {};

  for (int kt = 0; kt < 12; ++kt) {
    const int k0 = kt * 64;
    __syncthreads();
#pragma unroll
    for (int c = 0; c < 4; ++c) {
      const int chunk = c * 256 + tid;           // LDS 16B-slot index
      const int r = chunk >> 3;                  // local row 0..127
      const int cc = chunk & 7;                  // 16B column slot
      const int scc = cc ^ (r & 7);              // inverse-swizzled source col
      gl16(xbf + (rowBase + r) * 768 + k0 + scc * 8,
           &Ab[0][0] + (c * 2048 + wid * 512));
      gl16(Wbf + (size_t)(colBase + r) * 768 + k0 + scc * 8,
           &Bb[0][0] + (c * 2048 + wid * 512));
    }
    __syncthreads();
#pragma unroll
    for (int kk = 0; kk < 64; kk += 32) {
      short8 av[4], bv4[4];
#pragma unroll
      for (int rf = 0; rf < 4; ++rf) {
        const int row = wr * 64 + rf * 16 + lrow;
        const int cidx = ((kk >> 3) + lgrp) ^ (row & 7);   // swizzled read
        av[rf] = *(const short8*)&Ab[row][cidx * 8];
      }
#pragma unroll
      for (int cf = 0; cf < 4; ++cf) {
        const int row = wc * 64 + cf * 16 + lrow;
        const int cidx = ((kk >> 3) + lgrp) ^ (row & 7);
        bv4[cf] = *(const short8*)&Bb[row][cidx * 8];
      }
#pragma unroll
      for (int rf = 0; rf < 4; ++rf)
#pragma unroll
        for (int cf = 0; cf < 4; ++cf)
          acc[rf][cf] = __builtin_amdgcn_mfma_f32_16x16x32_bf16(
              av[rf], bv4[cf], acc[rf][cf], 0, 0, 0);
    }
  }

  // epilogue: bias + elu+1 (+mask), in place
  float bvv[4];
#pragma unroll
  for (int cf = 0; cf < 4; ++cf)
    bvv[cf] = bias[colBase + wc * 64 + cf * 16 + lrow];
#pragma unroll
  for (int rf = 0; rf < 4; ++rf)
#pragma unroll
    for (int cf = 0; cf < 4; ++cf)
#pragma unroll
      for (int j = 0; j < 4; ++j) {
        float v = acc[rf][cf][j] + bvv[cf];
        v = (v > 0.0f) ? (v + 1.0f) : __expf(v);
        if (MODE == 0) v *= rowf[wr * 64 + rf * 16 + lgrp * 4 + j];
        acc[rf][cf][j] = v;
      }

  const int head = colTile * 2 + wc;   // wave covers exactly one head (64 cols)

  // per-row reduction over the head's 64 cols: kd (MODE0) or q.ksum -> Z (MODE1)
#pragma unroll
  for (int rf = 0; rf < 4; ++rf)
#pragma unroll
    for (int j = 0; j < 4; ++j) {
      float s;
      if (MODE == 0) {
        s = acc[rf][0][j] + acc[rf][1][j] + acc[rf][2][j] + acc[rf][3][j];
      } else {
        s = acc[rf][0][j] * ksl[wc * 64 + 0 + lrow]
          + acc[rf][1][j] * ksl[wc * 64 + 16 + lrow]
          + acc[rf][2][j] * ksl[wc * 64 + 32 + lrow]
          + acc[rf][3][j] * ksl[wc * 64 + 48 + lrow];
      }
      s += __shfl_xor(s, 1, 64);
      s += __shfl_xor(s, 2, 64);
      s += __shfl_xor(s, 4, 64);
      s += __shfl_xor(s, 8, 64);
      if ((lane & 15) == 0) {
        const int t = trow * 128 + wr * 64 + rf * 16 + lgrp * 4 + j;
        if (MODE == 0)
          out0[((size_t)bm * 512 + t) * 12 + head] = s;
        else
          out0[((size_t)bm * 12 + head) * 512 + t] = 1.0f / (s + EPS_Z);
      }
    }

  if (MODE == 0) {
    // column sums (ksum partial over this 128-row tile)
#pragma unroll
    for (int cf = 0; cf < 4; ++cf) {
      float s = 0.f;
#pragma unroll
      for (int rf = 0; rf < 4; ++rf)
#pragma unroll
        for (int j = 0; j < 4; ++j) s += acc[rf][cf][j];
      s += __shfl_xor(s, 16, 64);
      s += __shfl_xor(s, 32, 64);
      if (lane < 16) kcol[wr][wc * 64 + cf * 16 + lane] = s;
    }
    __syncthreads();
    if (tid < 128)
      out1[((size_t)bm * 4 + trow) * 768 + colBase + tid] =
          kcol[0][tid] + kcol[1][tid];
  }
}

// ---------------- C: xk_part[bm][ts][n][c] = sum_{t in slice} kd[t][n] * x[t][c] ----------------
__global__ __launch_bounds__(192) void k_xk(const unsigned short* __restrict__ xbf,
                                            const float* __restrict__ kd,
                                            float* __restrict__ xk_part) {
  __shared__ float kdl[128][12];
  const int bm = blockIdx.x, ts = blockIdx.y, tid = threadIdx.x;
  for (int i = tid; i < 128 * 12; i += 192)
    kdl[i / 12][i % 12] = kd[((size_t)bm * 512 + ts * 128 + i / 12) * 12 + (i % 12)];
  __syncthreads();
  float a[12][4];
#pragma unroll
  for (int n = 0; n < 12; ++n)
#pragma unroll
    for (int j = 0; j < 4; ++j) a[n][j] = 0.f;
  const int c = tid * 4;
  const unsigned short* xp = xbf + ((size_t)bm * 512 + ts * 128) * 768 + c;
  for (int t = 0; t < 128; ++t) {
    ushort4 xv = *(const ushort4*)(xp + (size_t)t * 768);
    const float x0 = bf2f(xv.x), x1 = bf2f(xv.y), x2 = bf2f(xv.z), x3 = bf2f(xv.w);
#pragma unroll
    for (int n = 0; n < 12; ++n) {
      const float kv = kdl[t][n];
      a[n][0] += kv * x0; a[n][1] += kv * x1; a[n][2] += kv * x2; a[n][3] += kv * x3;
    }
  }
  float* op = xk_part + ((size_t)bm * 4 + ts) * 12 * 768 + c;
#pragma unroll
  for (int n = 0; n < 12; ++n)
    *(float4*)(op + (size_t)n * 768) = make_float4(a[n][0], a[n][1], a[n][2], a[n][3]);
}

// ---------------- D: S[n][e] then G[n][p], per bm ----------------
__global__ __launch_bounds__(256) void k_sg(const float* __restrict__ ksum_part,
                                            const float* __restrict__ xk_part,
                                            const float* __restrict__ Wv,
                                            const float* __restrict__ bv,
                                            const float* __restrict__ Wp,
                                            float* __restrict__ G) {
  __shared__ float ksum_l[768];
  __shared__ float kdsum_l[12];
  __shared__ __align__(16) float xk_l[12 * 768];
  __shared__ __align__(16) float S_l[12 * 64];
  const int bm = blockIdx.x, tid = threadIdx.x;
  for (int i = tid; i < 768; i += 256) {
    const float* kp = ksum_part + (size_t)bm * 4 * 768 + i;
    ksum_l[i] = kp[0] + kp[768] + kp[1536] + kp[2304];
  }
  for (int i = tid; i < 9216; i += 256) {
    const float* xp = xk_part + (size_t)bm * 4 * 9216 + i;
    xk_l[i] = xp[0] + xp[9216] + xp[18432] + xp[27648];
  }
  __syncthreads();
  if (tid < 12) {
    float s = 0.f;
    for (int d = 0; d < 64; ++d) s += ksum_l[tid * 64 + d];
    kdsum_l[tid] = s;
  }
  __syncthreads();
  for (int o = tid; o < 768; o += 256) {
    const int n = o >> 6;
    const float4* wv = (const float4*)(Wv + (size_t)o * 768);
    const float4* xp = (const float4*)(xk_l + n * 768);
    float s = 0.f;
    for (int c4 = 0; c4 < 192; ++c4) {
      float4 w = wv[c4], xx = xp[c4];
      s += w.x * xx.x + w.y * xx.y + w.z * xx.z + w.w * xx.w;
    }
    S_l[o] = s + bv[o] * kdsum_l[n];
  }
  __syncthreads();
  for (int p = tid; p < 768; p += 256) {
    const float4* wp = (const float4*)(Wp + (size_t)p * 768);
    for (int n = 0; n < 12; ++n) {
      const float4* sp = (const float4*)(S_l + n * 64);
      float g = 0.f;
#pragma unroll
      for (int e4 = 0; e4 < 16; ++e4) {
        float4 w = wp[n * 16 + e4], s = sp[e4];
        g += w.x * s.x + w.y * s.y + w.z * s.z + w.w * s.w;
      }
      G[((size_t)bm * 12 + n) * 768 + p] = g;
    }
  }
}

// ---------------- F: out[t][p] = bp[p] + sum_n Z[n][t]*G[n][p] ----------------
__global__ __launch_bounds__(256) void k_out(const float* __restrict__ Z,
                                             const float* __restrict__ G,
                                             const float* __restrict__ bp,
                                             float* __restrict__ outp) {
  __shared__ __align__(16) float G_l[9216];
  __shared__ float Z_l[768];
  __shared__ __align__(16) float bp_l[768];
  const int bm = blockIdx.x;
  const int tbase = blockIdx.y * 64;
  const int tid = threadIdx.x;
  for (int i = tid; i < 9216; i += 256) G_l[i] = G[(size_t)bm * 9216 + i];
  for (int i = tid; i < 768; i += 256) {
    bp_l[i] = bp[i];
    Z_l[i] = Z[((size_t)bm * 12 + (i >> 6)) * 512 + tbase + (i & 63)];
  }
  __syncthreads();
  for (int it = 0; it < 48; ++it) {
    const int idx = it * 1024 + tid * 4;
    const int t = idx / 768;
    const int p = idx - t * 768;
    float4 o = *(const float4*)&bp_l[p];
#pragma unroll
    for (int n = 0; n < 12; ++n) {
      const float z = Z_l[n * 64 + t];
      const float4 g = *(const float4*)&G_l[n * 768 + p];
      o.x += z * g.x; o.y += z * g.y; o.z += z * g.z; o.w += z * g.w;
    }
    *(float4*)&outp[((size_t)bm * 512 + tbase + t) * 768 + p] = o;
  }
}

extern "C" void kernel_launch(void* const* d_in, const int* in_sizes, int n_in,
                              void* d_out, int out_size, void* d_ws, size_t ws_size,
                              hipStream_t stream) {
  const float* x    = (const float*)d_in[0];
  const float* mask = (const float*)d_in[1];
  const float* Wq   = (const float*)d_in[2];
  const float* bq   = (const float*)d_in[3];
  const float* Wk   = (const float*)d_in[4];
  const float* bk   = (const float*)d_in[5];
  const float* Wv   = (const float*)d_in[6];
  const float* bv   = (const float*)d_in[7];
  const float* Wp   = (const float*)d_in[8];
  const float* bp   = (const float*)d_in[9];
  float* outp = (float*)d_out;

  char* ws = (char*)d_ws;
  unsigned short* xbf  = (unsigned short*)(ws);                  // 100,663,296 B
  unsigned short* Wkbf = (unsigned short*)(ws + 100663296);      //   1,179,648
  unsigned short* Wqbf = (unsigned short*)(ws + 101842944);      //   1,179,648
  float* kd        = (float*)(ws + 103022592);                   //   3,145,728
  float* ksum_part = (float*)(ws + 106168320);                   //   1,572,864
  float* xk_part   = (float*)(ws + 107741184);                   //  18,874,368
  float* Zb        = (float*)(ws + 126615552);                   //   3,145,728
  float* G         = (float*)(ws + 129761280);                   //   4,718,592
  // total ws: 134,479,872 B

  hipLaunchKernelGGL(k_cvt, dim3(24576), dim3(256), 0, stream, x, xbf, 50331648);
  hipLaunchKernelGGL(k_cvt, dim3(288), dim3(256), 0, stream, Wk, Wkbf, 589824);
  hipLaunchKernelGGL(k_cvt, dim3(288), dim3(256), 0, stream, Wq, Wqbf, 589824);
  hipLaunchKernelGGL((k_proj<0>), dim3(6, 512), dim3(256), 0, stream,
                     xbf, Wkbf, bk, mask, (const float*)nullptr, kd, ksum_part);
  hipLaunchKernelGGL(k_xk, dim3(128, 4), dim3(192), 0, stream, xbf, kd, xk_part);
  hipLaunchKernelGGL(k_sg, dim3(128), dim3(256), 0, stream,
                     ksum_part, xk_part, Wv, bv, Wp, G);
  hipLaunchKernelGGL((k_proj<1>), dim3(6, 512), dim3(256), 0, stream,
                     xbf, Wqbf, bq, (const float*)nullptr, ksum_part, Zb,
                     (float*)nullptr);
  hipLaunchKernelGGL(k_out, dim3(128, 8), dim3(256), 0, stream, Zb, G, bp, outp);
}

// Round 3
// 544.347 us; speedup vs baseline: 1.1952x; 1.0522x over previous
//
#include <hip/hip_runtime.h>
#include <hip/hip_bf16.h>
#include <stdint.h>

typedef short short8 __attribute__((ext_vector_type(8)));
typedef float f32x4 __attribute__((ext_vector_type(4)));

#define EPS_Z 1e-6f

__device__ __forceinline__ unsigned short f2bf(float f) {
  uint32_t b = __float_as_uint(f);
  b += 0x7FFFu + ((b >> 16) & 1u);   // RNE
  return (unsigned short)(b >> 16);
}
__device__ __forceinline__ float bf2f(unsigned short u) {
  return __uint_as_float(((uint32_t)u) << 16);
}

__device__ __forceinline__ void gl16(const unsigned short* g, unsigned short* l) {
  __builtin_amdgcn_global_load_lds(
      (const __attribute__((address_space(1))) unsigned int*)g,
      (__attribute__((address_space(3))) unsigned int*)l, 16, 0, 0);
}

// ---------------- P: fp32 -> bf16 convert (n multiple of 8) ----------------
__global__ __launch_bounds__(256) void k_cvt(const float* __restrict__ in,
                                             unsigned short* __restrict__ out, int n) {
  int i = (blockIdx.x * 256 + threadIdx.x) * 8;
  if (i >= n) return;
  float4 a = *(const float4*)(in + i);
  float4 b = *(const float4*)(in + i + 4);
  union { unsigned short u[8]; short8 v; } r;
  r.u[0] = f2bf(a.x); r.u[1] = f2bf(a.y); r.u[2] = f2bf(a.z); r.u[3] = f2bf(a.w);
  r.u[4] = f2bf(b.x); r.u[5] = f2bf(b.y); r.u[6] = f2bf(b.z); r.u[7] = f2bf(b.w);
  *(short8*)(out + i) = r.v;
}

// ---------------- A/E: projection GEMM + fused reductions ----------------
// MODE 0: k = elu(x@Wk^T+bk)+1, *mask; writes kd[bm][t][head], ksum_part[bm][trow][col]
// MODE 1: q = elu(x@Wq^T+bq)+1; writes Z[bm][head][t] = 1/(q . ksum + eps)
// grid (6 colTiles, 512 rowTiles) -- colTile fastest so the concurrent window
// covers all 6 colTiles of each rowTile (x tile HBM-fetched once, L3 re-read).
// 256 threads (4 waves, 2x2, each 64x64 of the 128x128 tile).
// LDS tiles are XOR-swizzled at 16B-chunk granularity (chunk ^= row&7):
// linear gl16 dest + inverse-swizzled GLOBAL source + swizzled ds_read (rule 21).
template <int MODE>
__global__ __launch_bounds__(256) void k_proj(
    const unsigned short* __restrict__ xbf,   // [65536][768] bf16
    const unsigned short* __restrict__ Wbf,   // [768][768] bf16
    const float* __restrict__ bias,           // [768]
    const float* __restrict__ mask,           // [128][512]      (MODE 0)
    const float* __restrict__ ksum_part,      // [128][4][768]   (MODE 1 input)
    float* __restrict__ out0,                 // MODE0: kd ; MODE1: Z
    float* __restrict__ out1)                 // MODE0: ksum_part
{
  __shared__ unsigned short Ab[128][64];   // 16KB
  __shared__ unsigned short Bb[128][64];   // 16KB
  __shared__ float rowf[128];
  __shared__ float ksl[128];
  __shared__ float kcol[2][128];

  const int tid = threadIdx.x;
  const int lane = tid & 63;
  const int wid = tid >> 6;
  const int wr = wid >> 1, wc = wid & 1;
  const int colTile = blockIdx.x;   // 0..5
  const int rowTile = blockIdx.y;   // 0..511
  const int bm = rowTile >> 2;
  const int trow = rowTile & 3;
  const size_t rowBase = (size_t)rowTile * 128;
  const int colBase = colTile * 128;
  const int lrow = lane & 15;
  const int lgrp = lane >> 4;

  if (MODE == 0) {
    if (tid < 128) rowf[tid] = mask[bm * 512 + trow * 128 + tid];
  } else {
    if (tid < 128) {
      const float* kp = ksum_part + (size_t)bm * 4 * 768 + colBase + tid;
      ksl[tid] = kp[0] + kp[768] + kp[1536] + kp[2304];
    }
  }

  f32x4 acc[4][4] = {};

  for (int kt = 0; kt < 12; ++kt) {
    const int k0 = kt * 64;
    __syncthreads();
#pragma unroll
    for (int c = 0; c < 4; ++c) {
      const int chunk = c * 256 + tid;           // LDS 16B-slot index
      const int r = chunk >> 3;                  // local row 0..127
      const int cc = chunk & 7;                  // 16B column slot
      const int scc = cc ^ (r & 7);              // inverse-swizzled source col
      gl16(xbf + (rowBase + r) * 768 + k0 + scc * 8,
           &Ab[0][0] + (c * 2048 + wid * 512));
      gl16(Wbf + (size_t)(colBase + r) * 768 + k0 + scc * 8,
           &Bb[0][0] + (c * 2048 + wid * 512));
    }
    __syncthreads();
#pragma unroll
    for (int kk = 0; kk < 64; kk += 32) {
      short8 av[4], bv4[4];
#pragma unroll
      for (int rf = 0; rf < 4; ++rf) {
        const int row = wr * 64 + rf * 16 + lrow;
        const int cidx = ((kk >> 3) + lgrp) ^ (row & 7);   // swizzled read
        av[rf] = *(const short8*)&Ab[row][cidx * 8];
      }
#pragma unroll
      for (int cf = 0; cf < 4; ++cf) {
        const int row = wc * 64 + cf * 16 + lrow;
        const int cidx = ((kk >> 3) + lgrp) ^ (row & 7);
        bv4[cf] = *(const short8*)&Bb[row][cidx * 8];
      }
#pragma unroll
      for (int rf = 0; rf < 4; ++rf)
#pragma unroll
        for (int cf = 0; cf < 4; ++cf)
          acc[rf][cf] = __builtin_amdgcn_mfma_f32_16x16x32_bf16(
              av[rf], bv4[cf], acc[rf][cf], 0, 0, 0);
    }
  }

  // epilogue: bias + elu+1 (+mask), in place
  float bvv[4];
#pragma unroll
  for (int cf = 0; cf < 4; ++cf)
    bvv[cf] = bias[colBase + wc * 64 + cf * 16 + lrow];
#pragma unroll
  for (int rf = 0; rf < 4; ++rf)
#pragma unroll
    for (int cf = 0; cf < 4; ++cf)
#pragma unroll
      for (int j = 0; j < 4; ++j) {
        float v = acc[rf][cf][j] + bvv[cf];
        v = (v > 0.0f) ? (v + 1.0f) : __expf(v);
        if (MODE == 0) v *= rowf[wr * 64 + rf * 16 + lgrp * 4 + j];
        acc[rf][cf][j] = v;
      }

  const int head = colTile * 2 + wc;   // wave covers exactly one head (64 cols)

  // per-row reduction over the head's 64 cols: kd (MODE0) or q.ksum -> Z (MODE1)
#pragma unroll
  for (int rf = 0; rf < 4; ++rf)
#pragma unroll
    for (int j = 0; j < 4; ++j) {
      float s;
      if (MODE == 0) {
        s = acc[rf][0][j] + acc[rf][1][j] + acc[rf][2][j] + acc[rf][3][j];
      } else {
        s = acc[rf][0][j] * ksl[wc * 64 + 0 + lrow]
          + acc[rf][1][j] * ksl[wc * 64 + 16 + lrow]
          + acc[rf][2][j] * ksl[wc * 64 + 32 + lrow]
          + acc[rf][3][j] * ksl[wc * 64 + 48 + lrow];
      }
      s += __shfl_xor(s, 1, 64);
      s += __shfl_xor(s, 2, 64);
      s += __shfl_xor(s, 4, 64);
      s += __shfl_xor(s, 8, 64);
      if ((lane & 15) == 0) {
        const int t = trow * 128 + wr * 64 + rf * 16 + lgrp * 4 + j;
        if (MODE == 0)
          out0[((size_t)bm * 512 + t) * 12 + head] = s;
        else
          out0[((size_t)bm * 12 + head) * 512 + t] = 1.0f / (s + EPS_Z);
      }
    }

  if (MODE == 0) {
    // column sums (ksum partial over this 128-row tile)
#pragma unroll
    for (int cf = 0; cf < 4; ++cf) {
      float s = 0.f;
#pragma unroll
      for (int rf = 0; rf < 4; ++rf)
#pragma unroll
        for (int j = 0; j < 4; ++j) s += acc[rf][cf][j];
      s += __shfl_xor(s, 16, 64);
      s += __shfl_xor(s, 32, 64);
      if (lane < 16) kcol[wr][wc * 64 + cf * 16 + lane] = s;
    }
    __syncthreads();
    if (tid < 128)
      out1[((size_t)bm * 4 + trow) * 768 + colBase + tid] =
          kcol[0][tid] + kcol[1][tid];
  }
}

// ---------------- C: xk_part[bm][ts][n][c] = sum_{t in slice} kd[t][n] * x[t][c] ----------------
__global__ __launch_bounds__(192) void k_xk(const unsigned short* __restrict__ xbf,
                                            const float* __restrict__ kd,
                                            float* __restrict__ xk_part) {
  __shared__ float kdl[128][12];
  const int bm = blockIdx.x, ts = blockIdx.y, tid = threadIdx.x;
  for (int i = tid; i < 128 * 12; i += 192)
    kdl[i / 12][i % 12] = kd[((size_t)bm * 512 + ts * 128 + i / 12) * 12 + (i % 12)];
  __syncthreads();
  float a[12][4];
#pragma unroll
  for (int n = 0; n < 12; ++n)
#pragma unroll
    for (int j = 0; j < 4; ++j) a[n][j] = 0.f;
  const int c = tid * 4;
  const unsigned short* xp = xbf + ((size_t)bm * 512 + ts * 128) * 768 + c;
  for (int t = 0; t < 128; ++t) {
    ushort4 xv = *(const ushort4*)(xp + (size_t)t * 768);
    const float x0 = bf2f(xv.x), x1 = bf2f(xv.y), x2 = bf2f(xv.z), x3 = bf2f(xv.w);
#pragma unroll
    for (int n = 0; n < 12; ++n) {
      const float kv = kdl[t][n];
      a[n][0] += kv * x0; a[n][1] += kv * x1; a[n][2] += kv * x2; a[n][3] += kv * x3;
    }
  }
  float* op = xk_part + ((size_t)bm * 4 + ts) * 12 * 768 + c;
#pragma unroll
  for (int n = 0; n < 12; ++n)
    *(float4*)(op + (size_t)n * 768) = make_float4(a[n][0], a[n][1], a[n][2], a[n][3]);
}

// ---------------- D: per (bm, head): S[64] then G[bm][n][0..767] ----------------
// grid (128 bm, 12 n), 256 threads. Weights L2-hot (all bm share Wv/Wp).
__global__ __launch_bounds__(256) void k_sg(const float* __restrict__ ksum_part,
                                            const float* __restrict__ xk_part,
                                            const float* __restrict__ Wv,
                                            const float* __restrict__ bv,
                                            const float* __restrict__ Wp,
                                            float* __restrict__ G) {
  __shared__ __align__(16) float xk_l[768];
  __shared__ __align__(16) float S_l[64];
  __shared__ float kdsum_s;
  const int bm = blockIdx.x, n = blockIdx.y, tid = threadIdx.x;

  if (tid < 192) {
    // xk[bm,n,c] = sum of 4 t-slice partials
    const float* xp = xk_part + (size_t)bm * 4 * 9216 + n * 768 + tid * 4;
    float4 a = *(const float4*)(xp);
    float4 b = *(const float4*)(xp + 9216);
    float4 c = *(const float4*)(xp + 18432);
    float4 d = *(const float4*)(xp + 27648);
    *(float4*)&xk_l[tid * 4] = make_float4(a.x + b.x + c.x + d.x,
                                           a.y + b.y + c.y + d.y,
                                           a.z + b.z + c.z + d.z,
                                           a.w + b.w + c.w + d.w);
  } else {
    // kdsum[n] = sum_d ksum[bm, n*64+d]  (wave 3, lanes 0..63)
    const int d = tid - 192;
    const float* kp = ksum_part + (size_t)bm * 4 * 768 + n * 64 + d;
    float s = kp[0] + kp[768] + kp[1536] + kp[2304];
    s += __shfl_xor(s, 1, 64);
    s += __shfl_xor(s, 2, 64);
    s += __shfl_xor(s, 4, 64);
    s += __shfl_xor(s, 8, 64);
    s += __shfl_xor(s, 16, 64);
    s += __shfl_xor(s, 32, 64);
    if (d == 0) kdsum_s = s;
  }
  __syncthreads();

  // S[e] = xk . Wv[n*64+e] + bv[n*64+e]*kdsum ; 4 threads per e
  {
    const int e = tid >> 2, q = tid & 3;
    const float4* wv = (const float4*)(Wv + (size_t)(n * 64 + e) * 768 + q * 192);
    const float4* xp4 = (const float4*)(xk_l + q * 192);
    float s = 0.f;
#pragma unroll
    for (int i = 0; i < 48; ++i) {
      float4 w = wv[i], xx = xp4[i];
      s += w.x * xx.x + w.y * xx.y + w.z * xx.z + w.w * xx.w;
    }
    s += __shfl_xor(s, 1, 64);
    s += __shfl_xor(s, 2, 64);
    if (q == 0) S_l[e] = s + bv[n * 64 + e] * kdsum_s;
  }
  __syncthreads();

  // G[bm][n][p] = S . Wp[p][n*64 .. n*64+63]
#pragma unroll
  for (int r = 0; r < 3; ++r) {
    const int p = r * 256 + tid;
    const float4* wp = (const float4*)(Wp + (size_t)p * 768 + n * 64);
    const float4* sp = (const float4*)S_l;
    float g = 0.f;
#pragma unroll
    for (int i = 0; i < 16; ++i) {
      float4 w = wp[i], s = sp[i];
      g += w.x * s.x + w.y * s.y + w.z * s.z + w.w * s.w;
    }
    G[((size_t)bm * 12 + n) * 768 + p] = g;
  }
}

// ---------------- F: out[t][p] = bp[p] + sum_n Z[n][t]*G[n][p] ----------------
__global__ __launch_bounds__(256) void k_out(const float* __restrict__ Z,
                                             const float* __restrict__ G,
                                             const float* __restrict__ bp,
                                             float* __restrict__ outp) {
  __shared__ __align__(16) float G_l[9216];
  __shared__ float Z_l[768];
  __shared__ __align__(16) float bp_l[768];
  const int bm = blockIdx.x;
  const int tbase = blockIdx.y * 64;
  const int tid = threadIdx.x;
  for (int i = tid; i < 9216; i += 256) G_l[i] = G[(size_t)bm * 9216 + i];
  for (int i = tid; i < 768; i += 256) {
    bp_l[i] = bp[i];
    Z_l[i] = Z[((size_t)bm * 12 + (i >> 6)) * 512 + tbase + (i & 63)];
  }
  __syncthreads();
  for (int it = 0; it < 48; ++it) {
    const int idx = it * 1024 + tid * 4;
    const int t = idx / 768;
    const int p = idx - t * 768;
    float4 o = *(const float4*)&bp_l[p];
#pragma unroll
    for (int n = 0; n < 12; ++n) {
      const float z = Z_l[n * 64 + t];
      const float4 g = *(const float4*)&G_l[n * 768 + p];
      o.x += z * g.x; o.y += z * g.y; o.z += z * g.z; o.w += z * g.w;
    }
    *(float4*)&outp[((size_t)bm * 512 + tbase + t) * 768 + p] = o;
  }
}

extern "C" void kernel_launch(void* const* d_in, const int* in_sizes, int n_in,
                              void* d_out, int out_size, void* d_ws, size_t ws_size,
                              hipStream_t stream) {
  const float* x    = (const float*)d_in[0];
  const float* mask = (const float*)d_in[1];
  const float* Wq   = (const float*)d_in[2];
  const float* bq   = (const float*)d_in[3];
  const float* Wk   = (const float*)d_in[4];
  const float* bk   = (const float*)d_in[5];
  const float* Wv   = (const float*)d_in[6];
  const float* bv   = (const float*)d_in[7];
  const float* Wp   = (const float*)d_in[8];
  const float* bp   = (const float*)d_in[9];
  float* outp = (float*)d_out;

  char* ws = (char*)d_ws;
  unsigned short* xbf  = (unsigned short*)(ws);                  // 100,663,296 B
  unsigned short* Wkbf = (unsigned short*)(ws + 100663296);      //   1,179,648
  unsigned short* Wqbf = (unsigned short*)(ws + 101842944);      //   1,179,648
  float* kd        = (float*)(ws + 103022592);                   //   3,145,728
  float* ksum_part = (float*)(ws + 106168320);                   //   1,572,864
  float* xk_part   = (float*)(ws + 107741184);                   //  18,874,368
  float* Zb        = (float*)(ws + 126615552);                   //   3,145,728
  float* G         = (float*)(ws + 129761280);                   //   4,718,592
  // total ws: 134,479,872 B

  hipLaunchKernelGGL(k_cvt, dim3(24576), dim3(256), 0, stream, x, xbf, 50331648);
  hipLaunchKernelGGL(k_cvt, dim3(288), dim3(256), 0, stream, Wk, Wkbf, 589824);
  hipLaunchKernelGGL(k_cvt, dim3(288), dim3(256), 0, stream, Wq, Wqbf, 589824);
  hipLaunchKernelGGL((k_proj<0>), dim3(6, 512), dim3(256), 0, stream,
                     xbf, Wkbf, bk, mask, (const float*)nullptr, kd, ksum_part);
  hipLaunchKernelGGL(k_xk, dim3(128, 4), dim3(192), 0, stream, xbf, kd, xk_part);
  hipLaunchKernelGGL(k_sg, dim3(128, 12), dim3(256), 0, stream,
                     ksum_part, xk_part, Wv, bv, Wp, G);
  hipLaunchKernelGGL((k_proj<1>), dim3(6, 512), dim3(256), 0, stream,
                     xbf, Wqbf, bq, (const float*)nullptr, ksum_part, Zb,
                     (float*)nullptr);
  hipLaunchKernelGGL(k_out, dim3(128, 8), dim3(256), 0, stream, Zb, G, bp, outp);
}